// Round 1
// baseline (5895.559 us; speedup 1.0000x reference)
//
#include <hip/hip_runtime.h>

#define BSZ   8192
#define NAG   16
#define NOBSZ 512
#define HSZ   64

__device__ __forceinline__ float sigmoid_f(float x) { return 1.f / (1.f + __expf(-x)); }
__device__ __forceinline__ float tanh_f(float x)    { float e = __expf(2.f * x); return 1.f - 2.f / (e + 1.f); }

// ---------------------------------------------------------------------------
// Encode: per-agent  e1 = relu(obs@W1^T+b1)  -> e2 = relu(e1@W2^T+b2)
//         X = (e2 + comm_t) @ W_ih^T + (b_ih + b_hh)     (gate preactivation,
//         input-side part of the LSTM, hoisted out of the scan)
// One workgroup = (agent n, 64 batch rows). 256 threads, fp32, LDS-tiled.
// ---------------------------------------------------------------------------
__global__ __launch_bounds__(256, 2) void encode_kernel(
    const float* __restrict__ obs, const float* __restrict__ comm,
    const float* __restrict__ W1,  const float* __restrict__ b1,
    const float* __restrict__ W2,  const float* __restrict__ b2,
    const float* __restrict__ Wih, const float* __restrict__ bih,
    const float* __restrict__ bhh, float* __restrict__ X)
{
    __shared__ float lds[20480];            // 80 KB -> 2 blocks/CU
    const int n  = blockIdx.y;
    const int bt = blockIdx.x;              // rows bt*64 .. bt*64+63
    const int t  = threadIdx.x;
    const int ty = t >> 4, tx = t & 15;

    float* sA   = lds;                      // [32][64]   GEMM1 A-tile (k-major)
    float* sW   = lds + 2048;               // [32][128]  GEMM1 W-tile (k-major)
    float* sW2  = lds;                      // [128][64]  GEMM2 W (aliases sA/sW)
    float* sE1  = lds + 8192;               // [128][64]  e1 (k-major)
    float* sE2  = lds + 16384;              // [64][64]   e2 (k-major)
    float* sWih = lds;                      // [64][256]  W_ih (aliases [0,16384))

    // ---------------- GEMM1: K=512, out 64x128 ----------------
    float acc1[4][2][4];
    #pragma unroll
    for (int i = 0; i < 4; i++)
        #pragma unroll
        for (int c = 0; c < 2; c++)
            #pragma unroll
            for (int j = 0; j < 4; j++) acc1[i][c][j] = 0.f;

    const float* obsn = obs + ((size_t)bt * 64 * NAG + n) * NOBSZ;
    const int rA = t >> 2, sgA = t & 3;     // A staging: 4 threads/row
    const int hW = t >> 1, sbW = (t & 1) * 4; // W staging: 2 threads/row

    for (int k0 = 0; k0 < NOBSZ; k0 += 32) {
        {   // stage A-tile (64 x 32), coalesced float4 loads, k-major LDS
            const float* src = obsn + (size_t)rA * (NAG * NOBSZ) + k0 + sgA * 4;
            float4 v0 = *(const float4*)src;
            float4 v1 = *(const float4*)(src + 16);
            sA[(sgA*4+ 0)*64 + rA] = v0.x; sA[(sgA*4+ 1)*64 + rA] = v0.y;
            sA[(sgA*4+ 2)*64 + rA] = v0.z; sA[(sgA*4+ 3)*64 + rA] = v0.w;
            sA[(sgA*4+16)*64 + rA] = v1.x; sA[(sgA*4+17)*64 + rA] = v1.y;
            sA[(sgA*4+18)*64 + rA] = v1.z; sA[(sgA*4+19)*64 + rA] = v1.w;
        }
        {   // stage W1-tile (128 x 32)
            const float* src = W1 + ((size_t)n * 128 + hW) * NOBSZ + k0;
            #pragma unroll
            for (int u = 0; u < 4; u++) {
                float4 v = *(const float4*)(src + (sbW + u) * 4);
                sW[((sbW+u)*4+0)*128 + hW] = v.x;
                sW[((sbW+u)*4+1)*128 + hW] = v.y;
                sW[((sbW+u)*4+2)*128 + hW] = v.z;
                sW[((sbW+u)*4+3)*128 + hW] = v.w;
            }
        }
        __syncthreads();
        #pragma unroll 8
        for (int kk = 0; kk < 32; ++kk) {
            float4 a   = *(const float4*)&sA[kk*64 + ty*4];
            float4 bv0 = *(const float4*)&sW[kk*128 + tx*4];
            float4 bv1 = *(const float4*)&sW[kk*128 + 64 + tx*4];
            float av[4] = {a.x, a.y, a.z, a.w};
            float w0[4] = {bv0.x, bv0.y, bv0.z, bv0.w};
            float w1[4] = {bv1.x, bv1.y, bv1.z, bv1.w};
            #pragma unroll
            for (int i = 0; i < 4; i++) {
                #pragma unroll
                for (int j = 0; j < 4; j++) {
                    acc1[i][0][j] += av[i] * w0[j];
                    acc1[i][1][j] += av[i] * w1[j];
                }
            }
        }
        __syncthreads();
    }
    {   // epilogue 1: relu(+b1) -> sE1 (k-major)
        const float* b1n = b1 + n * 128;
        #pragma unroll
        for (int i = 0; i < 4; i++) {
            int row = ty * 4 + i;
            #pragma unroll
            for (int c = 0; c < 2; c++) {
                #pragma unroll
                for (int j = 0; j < 4; j++) {
                    int col = c * 64 + tx * 4 + j;
                    sE1[col * 64 + row] = fmaxf(acc1[i][c][j] + b1n[col], 0.f);
                }
            }
        }
    }
    {   // stage W2 (64 x 128) into region P (sA/sW dead after last barrier)
        const int h = t >> 2, ks = t & 3;
        const float* src = W2 + ((size_t)n * 64 + h) * 128;
        #pragma unroll
        for (int u = 0; u < 8; u++) {
            int s = ks + 4 * u;
            float4 v = *(const float4*)(src + s * 4);
            sW2[(s*4+0)*64 + h] = v.x;
            sW2[(s*4+1)*64 + h] = v.y;
            sW2[(s*4+2)*64 + h] = v.z;
            sW2[(s*4+3)*64 + h] = v.w;
        }
    }
    __syncthreads();

    // ---------------- GEMM2: K=128, out 64x64 ----------------
    float acc2[4][4];
    #pragma unroll
    for (int i = 0; i < 4; i++)
        #pragma unroll
        for (int j = 0; j < 4; j++) acc2[i][j] = 0.f;
    #pragma unroll 8
    for (int kk = 0; kk < 128; ++kk) {
        float4 a = *(const float4*)&sE1[kk*64 + ty*4];
        float4 w = *(const float4*)&sW2[kk*64 + tx*4];
        float av[4] = {a.x, a.y, a.z, a.w};
        float wv[4] = {w.x, w.y, w.z, w.w};
        #pragma unroll
        for (int i = 0; i < 4; i++)
            #pragma unroll
            for (int j = 0; j < 4; j++) acc2[i][j] += av[i] * wv[j];
    }
    __syncthreads();                        // sE1/sW2 reads done
    {   // epilogue 2: relu(+b2) + comm_t -> sE2 (k-major)
        const float* b2n = b2 + n * 64;
        #pragma unroll
        for (int i = 0; i < 4; i++) {
            int row = ty * 4 + i;
            #pragma unroll
            for (int j = 0; j < 4; j++) {
                int col = tx * 4 + j;
                float v = fmaxf(acc2[i][j] + b2n[col], 0.f) + comm[col * NAG + n];
                sE2[col * 64 + row] = v;
            }
        }
    }
    {   // stage W_ih (256 x 64) -> sWih[k][r]
        const float* src = Wih + t * 64;
        #pragma unroll
        for (int u = 0; u < 16; u++) {
            float4 v = *(const float4*)(src + u * 4);
            sWih[(u*4+0)*256 + t] = v.x;
            sWih[(u*4+1)*256 + t] = v.y;
            sWih[(u*4+2)*256 + t] = v.z;
            sWih[(u*4+3)*256 + t] = v.w;
        }
    }
    __syncthreads();

    // ---------------- GEMM3: K=64, out 64x256 (two halves to cap VGPRs) ----
    for (int half = 0; half < 2; ++half) {
        float acc3[4][2][4];
        #pragma unroll
        for (int i = 0; i < 4; i++)
            #pragma unroll
            for (int c = 0; c < 2; c++)
                #pragma unroll
                for (int j = 0; j < 4; j++) acc3[i][c][j] = 0.f;
        #pragma unroll 4
        for (int kk = 0; kk < 64; ++kk) {
            float4 a = *(const float4*)&sE2[kk*64 + ty*4];
            float av[4] = {a.x, a.y, a.z, a.w};
            #pragma unroll
            for (int c = 0; c < 2; c++) {
                int col0 = (half * 2 + c) * 64 + tx * 4;
                float4 w = *(const float4*)&sWih[kk*256 + col0];
                float wv[4] = {w.x, w.y, w.z, w.w};
                #pragma unroll
                for (int i = 0; i < 4; i++)
                    #pragma unroll
                    for (int j = 0; j < 4; j++) acc3[i][c][j] += av[i] * wv[j];
            }
        }
        #pragma unroll
        for (int i = 0; i < 4; i++) {
            int b = bt * 64 + ty * 4 + i;
            float* dst = X + ((size_t)b * NAG + n) * 256;
            #pragma unroll
            for (int c = 0; c < 2; c++) {
                int col0 = (half * 2 + c) * 64 + tx * 4;
                float4 bi = *(const float4*)(bih + col0);
                float4 bh = *(const float4*)(bhh + col0);
                float4 o;
                o.x = acc3[i][c][0] + bi.x + bh.x;
                o.y = acc3[i][c][1] + bi.y + bh.y;
                o.z = acc3[i][c][2] + bi.z + bh.z;
                o.w = acc3[i][c][3] + bi.w + bh.w;
                *(float4*)(dst + col0) = o;
            }
        }
    }
}

// ---------------------------------------------------------------------------
// Scan: 16 independent agents -> 16 workgroups. 256 threads; thread r owns
// gate row r (W_hh row in 64 VGPRs); h broadcast via LDS; wave0 does gates.
// X already contains x@W_ih^T + comm-part + both biases.
// ---------------------------------------------------------------------------
__global__ __launch_bounds__(256, 1) void scan_kernel(
    const float* __restrict__ X, const float* __restrict__ Whh,
    const float* __restrict__ lstm_h, const float* __restrict__ lstm_s,
    float* __restrict__ hid)
{
    __shared__ float h_lds[64];
    __shared__ float g_lds[256];
    const int n = blockIdx.x;
    const int t = threadIdx.x;

    float4 w[16];
    const float* wr = Whh + t * 64;
    #pragma unroll
    for (int u = 0; u < 16; u++) w[u] = *(const float4*)(wr + u * 4);

    float c = 0.f;
    if (t < 64) {
        h_lds[t] = lstm_h[t * NAG + n];     // (1,1,H,N) -> h*16+n
        c        = lstm_s[t * NAG + n];
    }
    __syncthreads();

    const float* Xp = X + n * 256 + t;      // stride 16*256 per step
    float*       hp = hid + n * 64 + t;     // stride 16*64  per step (t<64)

    float xa[8], xb[8];
    #pragma unroll
    for (int i = 0; i < 8; i++) { xa[i] = Xp[(size_t)i * 4096]; xb[i] = 0.f; }

    for (int b0 = 0; b0 < BSZ; b0 += 8) {
        if (b0 + 8 < BSZ) {                 // prefetch next group (hides HBM/L3)
            #pragma unroll
            for (int i = 0; i < 8; i++) xb[i] = Xp[(size_t)(b0 + 8 + i) * 4096];
        }
        #pragma unroll
        for (int i = 0; i < 8; i++) {
            float a0 = 0.f, a1 = 0.f, a2 = 0.f, a3 = 0.f;   // 4 chains for ILP
            const float4* h4 = (const float4*)h_lds;
            #pragma unroll
            for (int u = 0; u < 16; u += 4) {
                float4 h0 = h4[u+0], h1 = h4[u+1], h2 = h4[u+2], h3 = h4[u+3];
                a0 += w[u+0].x*h0.x + w[u+0].y*h0.y + w[u+0].z*h0.z + w[u+0].w*h0.w;
                a1 += w[u+1].x*h1.x + w[u+1].y*h1.y + w[u+1].z*h1.z + w[u+1].w*h1.w;
                a2 += w[u+2].x*h2.x + w[u+2].y*h2.y + w[u+2].z*h2.z + w[u+2].w*h2.w;
                a3 += w[u+3].x*h3.x + w[u+3].y*h3.y + w[u+3].z*h3.z + w[u+3].w*h3.w;
            }
            g_lds[t] = xa[i] + ((a0 + a1) + (a2 + a3));
            __syncthreads();
            if (t < 64) {
                float gi = g_lds[t], gf = g_lds[64 + t];
                float gg = g_lds[128 + t], go = g_lds[192 + t];
                float is = sigmoid_f(gi);
                float fs = sigmoid_f(gf);
                float gs = tanh_f(gg);
                float os = sigmoid_f(go);
                c = fs * c + is * gs;
                float hh = os * tanh_f(c);
                h_lds[t] = hh;
                hp[(size_t)(b0 + i) * (NAG * 64)] = hh;
            }
            __syncthreads();
        }
        #pragma unroll
        for (int i = 0; i < 8; i++) xa[i] = xb[i];
    }
}

// ---------------------------------------------------------------------------
// Decode: q[b,n,a] = hidden[b,n,:] . Wd[n,a,:] + bd[n,a]. Memory-bound.
// ---------------------------------------------------------------------------
__global__ __launch_bounds__(256) void decode_kernel(
    const float* __restrict__ hid, const float* __restrict__ Wd,
    const float* __restrict__ bd, float* __restrict__ q)
{
    int g   = blockIdx.x * 256 + threadIdx.x;   // [0, B*N*A)
    int row = g >> 4;                            // b*16+n
    int a   = g & 15;
    int n   = row & 15;
    const float4* hr = (const float4*)(hid + (size_t)row * 64);
    const float4* wr = (const float4*)(Wd + ((size_t)n * 16 + a) * 64);
    float s0 = 0.f, s1 = 0.f, s2 = 0.f, s3 = 0.f;
    #pragma unroll
    for (int u = 0; u < 16; u += 4) {
        float4 h0 = hr[u+0], h1 = hr[u+1], h2 = hr[u+2], h3 = hr[u+3];
        float4 w0 = wr[u+0], w1 = wr[u+1], w2 = wr[u+2], w3 = wr[u+3];
        s0 += h0.x*w0.x + h0.y*w0.y + h0.z*w0.z + h0.w*w0.w;
        s1 += h1.x*w1.x + h1.y*w1.y + h1.z*w1.z + h1.w*w1.w;
        s2 += h2.x*w2.x + h2.y*w2.y + h2.z*w2.z + h2.w*w2.w;
        s3 += h3.x*w3.x + h3.y*w3.y + h3.z*w3.z + h3.w*w3.w;
    }
    q[g] = bd[n * 16 + a] + ((s0 + s1) + (s2 + s3));
}

extern "C" void kernel_launch(void* const* d_in, const int* in_sizes, int n_in,
                              void* d_out, int out_size, void* d_ws, size_t ws_size,
                              hipStream_t stream) {
    const float* obs    = (const float*)d_in[0];
    const float* lstm_h = (const float*)d_in[1];
    const float* lstm_s = (const float*)d_in[2];
    const float* comm   = (const float*)d_in[3];
    const float* W1     = (const float*)d_in[4];
    const float* b1     = (const float*)d_in[5];
    const float* W2     = (const float*)d_in[6];
    const float* b2     = (const float*)d_in[7];
    const float* W_ih   = (const float*)d_in[8];
    const float* W_hh   = (const float*)d_in[9];
    const float* b_ih   = (const float*)d_in[10];
    const float* b_hh   = (const float*)d_in[11];
    const float* Wd     = (const float*)d_in[12];
    const float* bd     = (const float*)d_in[13];
    float* q   = (float*)d_out;

    float* X   = (float*)d_ws;                       // (B*N, 256) f32 = 128 MB
    float* hid = (float*)d_ws + (size_t)BSZ * NAG * 256;  // (B*N, 64) f32 = 32 MB
    (void)in_sizes; (void)n_in; (void)out_size; (void)ws_size;

    encode_kernel<<<dim3(128, 16), 256, 0, stream>>>(obs, comm, W1, b1, W2, b2,
                                                     W_ih, b_ih, b_hh, X);
    scan_kernel<<<16, 256, 0, stream>>>(X, W_hh, lstm_h, lstm_s, hid);
    decode_kernel<<<(BSZ * NAG * 16) / 256, 256, 0, stream>>>(hid, Wd, bd, q);
}

// Round 3
// 3810.096 us; speedup vs baseline: 1.5474x; 1.5474x over previous
//
#include <hip/hip_runtime.h>

#define BSZ   8192
#define NAG   16
#define NOBSZ 512
#define HSZ   64

typedef _Float16 h2 __attribute__((ext_vector_type(2)));

__device__ __forceinline__ float sigmoid_f(float x) { return 1.f / (1.f + __expf(-x)); }
__device__ __forceinline__ float tanh_f(float x)    { float e = __expf(2.f * x); return 1.f - 2.f / (e + 1.f); }

// Barrier that does NOT drain vmcnt (keeps X prefetch / hid stores in flight).
// LDS visibility needs only lgkmcnt(0) before s_barrier.
__device__ __forceinline__ void lds_barrier() {
    asm volatile("s_waitcnt lgkmcnt(0)" ::: "memory");
    __builtin_amdgcn_s_barrier();
    asm volatile("" ::: "memory");
}

// ---------------------------------------------------------------------------
// Encode: per-agent  e1 = relu(obs@W1^T+b1)  -> e2 = relu(e1@W2^T+b2)
//         X = (e2 + comm_t) @ W_ih^T + (b_ih + b_hh)
// One workgroup = (agent n, 64 batch rows). 256 threads, fp32, LDS-tiled.
// ---------------------------------------------------------------------------
__global__ __launch_bounds__(256, 2) void encode_kernel(
    const float* __restrict__ obs, const float* __restrict__ comm,
    const float* __restrict__ W1,  const float* __restrict__ b1,
    const float* __restrict__ W2,  const float* __restrict__ b2,
    const float* __restrict__ Wih, const float* __restrict__ bih,
    const float* __restrict__ bhh, float* __restrict__ X)
{
    __shared__ float lds[20480];            // 80 KB -> 2 blocks/CU
    const int n  = blockIdx.y;
    const int bt = blockIdx.x;              // rows bt*64 .. bt*64+63
    const int t  = threadIdx.x;
    const int ty = t >> 4, tx = t & 15;

    float* sA   = lds;                      // [32][64]   GEMM1 A-tile (k-major)
    float* sW   = lds + 2048;               // [32][128]  GEMM1 W-tile (k-major)
    float* sW2  = lds;                      // [128][64]  GEMM2 W (aliases sA/sW)
    float* sE1  = lds + 8192;               // [128][64]  e1 (k-major)
    float* sE2  = lds + 16384;              // [64][64]   e2 (k-major)
    float* sWih = lds;                      // [64][256]  W_ih (aliases [0,16384))

    // ---------------- GEMM1: K=512, out 64x128 ----------------
    float acc1[4][2][4];
    #pragma unroll
    for (int i = 0; i < 4; i++)
        #pragma unroll
        for (int c = 0; c < 2; c++)
            #pragma unroll
            for (int j = 0; j < 4; j++) acc1[i][c][j] = 0.f;

    const float* obsn = obs + ((size_t)bt * 64 * NAG + n) * NOBSZ;
    const int rA = t >> 2, sgA = t & 3;     // A staging: 4 threads/row
    const int hW = t >> 1, sbW = (t & 1) * 4; // W staging: 2 threads/row

    for (int k0 = 0; k0 < NOBSZ; k0 += 32) {
        {   // stage A-tile (64 x 32), coalesced float4 loads, k-major LDS
            const float* src = obsn + (size_t)rA * (NAG * NOBSZ) + k0 + sgA * 4;
            float4 v0 = *(const float4*)src;
            float4 v1 = *(const float4*)(src + 16);
            sA[(sgA*4+ 0)*64 + rA] = v0.x; sA[(sgA*4+ 1)*64 + rA] = v0.y;
            sA[(sgA*4+ 2)*64 + rA] = v0.z; sA[(sgA*4+ 3)*64 + rA] = v0.w;
            sA[(sgA*4+16)*64 + rA] = v1.x; sA[(sgA*4+17)*64 + rA] = v1.y;
            sA[(sgA*4+18)*64 + rA] = v1.z; sA[(sgA*4+19)*64 + rA] = v1.w;
        }
        {   // stage W1-tile (128 x 32)
            const float* src = W1 + ((size_t)n * 128 + hW) * NOBSZ + k0;
            #pragma unroll
            for (int u = 0; u < 4; u++) {
                float4 v = *(const float4*)(src + (sbW + u) * 4);
                sW[((sbW+u)*4+0)*128 + hW] = v.x;
                sW[((sbW+u)*4+1)*128 + hW] = v.y;
                sW[((sbW+u)*4+2)*128 + hW] = v.z;
                sW[((sbW+u)*4+3)*128 + hW] = v.w;
            }
        }
        __syncthreads();
        #pragma unroll 8
        for (int kk = 0; kk < 32; ++kk) {
            float4 a   = *(const float4*)&sA[kk*64 + ty*4];
            float4 bv0 = *(const float4*)&sW[kk*128 + tx*4];
            float4 bv1 = *(const float4*)&sW[kk*128 + 64 + tx*4];
            float av[4] = {a.x, a.y, a.z, a.w};
            float w0[4] = {bv0.x, bv0.y, bv0.z, bv0.w};
            float w1[4] = {bv1.x, bv1.y, bv1.z, bv1.w};
            #pragma unroll
            for (int i = 0; i < 4; i++) {
                #pragma unroll
                for (int j = 0; j < 4; j++) {
                    acc1[i][0][j] += av[i] * w0[j];
                    acc1[i][1][j] += av[i] * w1[j];
                }
            }
        }
        __syncthreads();
    }
    {   // epilogue 1: relu(+b1) -> sE1 (k-major)
        const float* b1n = b1 + n * 128;
        #pragma unroll
        for (int i = 0; i < 4; i++) {
            int row = ty * 4 + i;
            #pragma unroll
            for (int c = 0; c < 2; c++) {
                #pragma unroll
                for (int j = 0; j < 4; j++) {
                    int col = c * 64 + tx * 4 + j;
                    sE1[col * 64 + row] = fmaxf(acc1[i][c][j] + b1n[col], 0.f);
                }
            }
        }
    }
    {   // stage W2 (64 x 128) into region P (sA/sW dead after last barrier)
        const int h = t >> 2, ks = t & 3;
        const float* src = W2 + ((size_t)n * 64 + h) * 128;
        #pragma unroll
        for (int u = 0; u < 8; u++) {
            int s = ks + 4 * u;
            float4 v = *(const float4*)(src + s * 4);
            sW2[(s*4+0)*64 + h] = v.x;
            sW2[(s*4+1)*64 + h] = v.y;
            sW2[(s*4+2)*64 + h] = v.z;
            sW2[(s*4+3)*64 + h] = v.w;
        }
    }
    __syncthreads();

    // ---------------- GEMM2: K=128, out 64x64 ----------------
    float acc2[4][4];
    #pragma unroll
    for (int i = 0; i < 4; i++)
        #pragma unroll
        for (int j = 0; j < 4; j++) acc2[i][j] = 0.f;
    #pragma unroll 8
    for (int kk = 0; kk < 128; ++kk) {
        float4 a = *(const float4*)&sE1[kk*64 + ty*4];
        float4 w = *(const float4*)&sW2[kk*64 + tx*4];
        float av[4] = {a.x, a.y, a.z, a.w};
        float wv[4] = {w.x, w.y, w.z, w.w};
        #pragma unroll
        for (int i = 0; i < 4; i++)
            #pragma unroll
            for (int j = 0; j < 4; j++) acc2[i][j] += av[i] * wv[j];
    }
    __syncthreads();                        // sE1/sW2 reads done
    {   // epilogue 2: relu(+b2) + comm_t -> sE2 (k-major)
        const float* b2n = b2 + n * 64;
        #pragma unroll
        for (int i = 0; i < 4; i++) {
            int row = ty * 4 + i;
            #pragma unroll
            for (int j = 0; j < 4; j++) {
                int col = tx * 4 + j;
                float v = fmaxf(acc2[i][j] + b2n[col], 0.f) + comm[col * NAG + n];
                sE2[col * 64 + row] = v;
            }
        }
    }
    {   // stage W_ih (256 x 64) -> sWih[k][r]
        const float* src = Wih + t * 64;
        #pragma unroll
        for (int u = 0; u < 16; u++) {
            float4 v = *(const float4*)(src + u * 4);
            sWih[(u*4+0)*256 + t] = v.x;
            sWih[(u*4+1)*256 + t] = v.y;
            sWih[(u*4+2)*256 + t] = v.z;
            sWih[(u*4+3)*256 + t] = v.w;
        }
    }
    __syncthreads();

    // ---------------- GEMM3: K=64, out 64x256 (two halves to cap VGPRs) ----
    for (int half = 0; half < 2; ++half) {
        float acc3[4][2][4];
        #pragma unroll
        for (int i = 0; i < 4; i++)
            #pragma unroll
            for (int c = 0; c < 2; c++)
                #pragma unroll
                for (int j = 0; j < 4; j++) acc3[i][c][j] = 0.f;
        #pragma unroll 4
        for (int kk = 0; kk < 64; ++kk) {
            float4 a = *(const float4*)&sE2[kk*64 + ty*4];
            float av[4] = {a.x, a.y, a.z, a.w};
            #pragma unroll
            for (int c = 0; c < 2; c++) {
                int col0 = (half * 2 + c) * 64 + tx * 4;
                float4 w = *(const float4*)&sWih[kk*256 + col0];
                float wv[4] = {w.x, w.y, w.z, w.w};
                #pragma unroll
                for (int i = 0; i < 4; i++)
                    #pragma unroll
                    for (int j = 0; j < 4; j++) acc3[i][c][j] += av[i] * wv[j];
            }
        }
        #pragma unroll
        for (int i = 0; i < 4; i++) {
            int b = bt * 64 + ty * 4 + i;
            float* dst = X + ((size_t)b * NAG + n) * 256;
            #pragma unroll
            for (int c = 0; c < 2; c++) {
                int col0 = (half * 2 + c) * 64 + tx * 4;
                float4 bi = *(const float4*)(bih + col0);
                float4 bh = *(const float4*)(bhh + col0);
                float4 o;
                o.x = acc3[i][c][0] + bi.x + bh.x;
                o.y = acc3[i][c][1] + bi.y + bh.y;
                o.z = acc3[i][c][2] + bi.z + bh.z;
                o.w = acc3[i][c][3] + bi.w + bh.w;
                *(float4*)(dst + col0) = o;
            }
        }
    }
}

// ---------------------------------------------------------------------------
// Scan: 16 independent agents -> 16 workgroups, 256 threads (4 waves).
// Wave w owns gate type w (rows w*64+j) and applies its nonlinearity in
// parallel BEFORE publishing. Every wave keeps a private c replica and a
// private f16 h buffer (written+read only by itself -> no barrier for h).
// Gates double-buffered -> ONE lgkm-only barrier per step (vmcnt never
// drained: X prefetch and hid stores stay in flight).
// W_hh held as 32 f16x2 dwords/thread feeding v_dot2_f32_f16.
// ---------------------------------------------------------------------------
__global__ __launch_bounds__(256, 1) void scan_kernel(
    const float* __restrict__ X, const float* __restrict__ Whh,
    const float* __restrict__ lstm_h, const float* __restrict__ lstm_s,
    float* __restrict__ hid)
{
    __shared__ __align__(16) _Float16 hbuf[4][64];   // per-wave private h (f16)
    __shared__ float g_lds[2][4][64];                // double-buffered activated gates
    const int n = blockIdx.x;
    const int t = threadIdx.x;
    const int w = t >> 6;            // wave id == gate type (0:i 1:f 2:g 3:o)
    const int j = t & 63;            // h index within gate

    // W_hh row t as 32 packed f16x2 (static indices only -> stays in VGPRs)
    h2 wreg[32];
    {
        const float* wr = Whh + (size_t)t * 64;
        #pragma unroll
        for (int u = 0; u < 16; u++) {
            float4 v = *(const float4*)(wr + u * 4);
            h2 p0, p1;
            p0.x = (_Float16)v.x; p0.y = (_Float16)v.y;
            p1.x = (_Float16)v.z; p1.y = (_Float16)v.w;
            wreg[2*u+0] = p0;
            wreg[2*u+1] = p1;
        }
    }

    // init: every wave replicates c[j]; each wave fills its own h buffer
    float c = lstm_s[j * NAG + n];                   // (1,1,H,N): h*16+n
    hbuf[w][j] = (_Float16)lstm_h[j * NAG + n];
    lds_barrier();

    const float* Xp = X + n * 256 + t;               // stride 16*256 per step
    float*       hp = hid + n * 64 + j;              // wave0 stores h

    float xa[8], xb[8];
    #pragma unroll
    for (int i = 0; i < 8; i++) { xa[i] = Xp[(size_t)i * 4096]; xb[i] = 0.f; }

    const float4* hb4 = (const float4*)hbuf[w];

    for (int b0 = 0; b0 < BSZ; b0 += 8) {
        if (b0 + 8 < BSZ) {                          // prefetch next group
            #pragma unroll
            for (int i = 0; i < 8; i++) xb[i] = Xp[(size_t)(b0 + 8 + i) * 4096];
        }
        #pragma unroll
        for (int i = 0; i < 8; i++) {
            const int p = i & 1;
            // ---- phase A: gate row t = dot(W_hh[t], h) + X, activated ----
            float a0 = 0.f, a1 = 0.f, a2 = 0.f, a3 = 0.f;
            #pragma unroll
            for (int u = 0; u < 8; u++) {
                float4 v = hb4[u];
                a0 = __builtin_amdgcn_fdot2(wreg[4*u+0], __builtin_bit_cast(h2, v.x), a0, false);
                a1 = __builtin_amdgcn_fdot2(wreg[4*u+1], __builtin_bit_cast(h2, v.y), a1, false);
                a2 = __builtin_amdgcn_fdot2(wreg[4*u+2], __builtin_bit_cast(h2, v.z), a2, false);
                a3 = __builtin_amdgcn_fdot2(wreg[4*u+3], __builtin_bit_cast(h2, v.w), a3, false);
            }
            float gp  = xa[i] + ((a0 + a1) + (a2 + a3));
            // wave 2 needs tanh = 2*sigmoid(2x)-1; others sigmoid. One exp path.
            float arg = (w == 2) ? 2.f * gp : gp;
            float sg  = 1.f / (1.f + __expf(-arg));
            float act = (w == 2) ? 2.f * sg - 1.f : sg;
            g_lds[p][w][j] = act;
            lds_barrier();                           // the ONLY barrier per step
            // ---- phase B: all waves redundantly combine (replicated c) ----
            float is = g_lds[p][0][j];
            float fs = g_lds[p][1][j];
            float gs = g_lds[p][2][j];
            float os = g_lds[p][3][j];
            c = fs * c + is * gs;
            float hh = os * tanh_f(c);
            hbuf[w][j] = (_Float16)hh;               // own buffer: no barrier
            if (t < 64) hp[(size_t)(b0 + i) * (NAG * 64)] = hh;
        }
        #pragma unroll
        for (int i = 0; i < 8; i++) xa[i] = xb[i];
    }
}

// ---------------------------------------------------------------------------
// Decode: q[b,n,a] = hidden[b,n,:] . Wd[n,a,:] + bd[n,a]. Memory-bound.
// ---------------------------------------------------------------------------
__global__ __launch_bounds__(256) void decode_kernel(
    const float* __restrict__ hid, const float* __restrict__ Wd,
    const float* __restrict__ bd, float* __restrict__ q)
{
    int g   = blockIdx.x * 256 + threadIdx.x;   // [0, B*N*A)
    int row = g >> 4;                            // b*16+n
    int a   = g & 15;
    int n   = row & 15;
    const float4* hr = (const float4*)(hid + (size_t)row * 64);
    const float4* wr = (const float4*)(Wd + ((size_t)n * 16 + a) * 64);
    float s0 = 0.f, s1 = 0.f, s2 = 0.f, s3 = 0.f;
    #pragma unroll
    for (int u = 0; u < 16; u += 4) {
        float4 h0 = hr[u+0], h1 = hr[u+1], h2v = hr[u+2], h3 = hr[u+3];
        float4 w0 = wr[u+0], w1 = wr[u+1], w2 = wr[u+2], w3 = wr[u+3];
        s0 += h0.x*w0.x + h0.y*w0.y + h0.z*w0.z + h0.w*w0.w;
        s1 += h1.x*w1.x + h1.y*w1.y + h1.z*w1.z + h1.w*w1.w;
        s2 += h2v.x*w2.x + h2v.y*w2.y + h2v.z*w2.z + h2v.w*w2.w;
        s3 += h3.x*w3.x + h3.y*w3.y + h3.z*w3.z + h3.w*w3.w;
    }
    q[g] = bd[n * 16 + a] + ((s0 + s1) + (s2 + s3));
}

extern "C" void kernel_launch(void* const* d_in, const int* in_sizes, int n_in,
                              void* d_out, int out_size, void* d_ws, size_t ws_size,
                              hipStream_t stream) {
    const float* obs    = (const float*)d_in[0];
    const float* lstm_h = (const float*)d_in[1];
    const float* lstm_s = (const float*)d_in[2];
    const float* comm   = (const float*)d_in[3];
    const float* W1     = (const float*)d_in[4];
    const float* b1     = (const float*)d_in[5];
    const float* W2     = (const float*)d_in[6];
    const float* b2     = (const float*)d_in[7];
    const float* W_ih   = (const float*)d_in[8];
    const float* W_hh   = (const float*)d_in[9];
    const float* b_ih   = (const float*)d_in[10];
    const float* b_hh   = (const float*)d_in[11];
    const float* Wd     = (const float*)d_in[12];
    const float* bd     = (const float*)d_in[13];
    float* q   = (float*)d_out;

    float* X   = (float*)d_ws;                       // (B*N, 256) f32 = 128 MB
    float* hid = (float*)d_ws + (size_t)BSZ * NAG * 256;  // (B*N, 64) f32 = 32 MB
    (void)in_sizes; (void)n_in; (void)out_size; (void)ws_size;

    encode_kernel<<<dim3(128, 16), 256, 0, stream>>>(obs, comm, W1, b1, W2, b2,
                                                     W_ih, b_ih, b_hh, X);
    scan_kernel<<<16, 256, 0, stream>>>(X, W_hh, lstm_h, lstm_s, hid);
    decode_kernel<<<(BSZ * NAG * 16) / 256, 256, 0, stream>>>(hid, Wd, bd, q);
}